// Round 1
// 182.211 us; speedup vs baseline: 1.0030x; 1.0030x over previous
//
#include <hip/hip_runtime.h>

// LSTM: T=512, B=4096, IN=1, H=12.
// R11 = R10 (best measured 133.8-136 us) + latency-path polish. Counters at
// R10: VALUBusy 59.6%, Occupancy 11% (1 wave/SIMD by design), bank conflicts
// 0, HBM 4.6% -> the step is LATENCY-bound on the serial chain; ~40% of
// cycles are dependency bubbles (two serial exp2->rcp pairs per step with
// nothing co-issuable). Changes:
//  - fc-reduce DELAYED one step: step t's ring-reduce + store now executes
//    inside step t+1's transcendental stall windows (split in two halves:
//    rors 8,4 in the gate exp2->rcp window; rors 2,1 + store in the
//    tanh(c) window). t=0 boundary handled branchlessly: the first (fake)
//    store aliases out[0][cell] and is overwritten by the real t=0 store
//    one step later (same lane, same address, program order). Final step
//    stored in an epilogue.
//  - x-projection + bias folded into the chain HEAD (gifA/goA init), not
//    appended after the ror block: -2 fma levels of critical path.
//  - xq prefetched ONE 4-step group ahead so the head-fold never waits on
//    lgkmcnt (R8/R9's regression was a different, branchy hoist).
//  - cell state carried pre-scaled: c2 = 2*log2(e)*c; recurrence
//    c2 = sf*c2 + si*tgS with scale folded into constants -> removes the
//    SPOS*cst multiply from the c->exp2 path.
// Rejected on theory: combined-reciprocal (saves 2 rcp ISSUE, adds 2 muls
// to the LATENCY path - wrong trade here); 4-way accumulator split (DPP
// issue serialization dominates, tree shape barely moves the path).
//
// Structure (stable since R6/R7):
//  - one cell per 16-lane DPP row (j = lane&15; lanes 12..15 finite clones),
//    4 cells/wave, 1024 single-wave blocks = every SIMD busy.
//  - h exchanged with 15 v_mov_b32 dpp row_ror (direction probed at setup;
//    per-source-slot weight tables, zero-gated for clone sources).
//  - gates: 2-way-split pk_fma chains, weights pre-scaled
//    (sigmoid: -log2e, tanh-g: +2log2e) so activations are rcp(1+exp2(g)).
//  - X: chunk of 64 steps staged to LDS transposed [row][time] (XPAD=68
//    kills bank conflicts), global prefetch one chunk ahead.
//  - launch_bounds(64,1): no spills (R4 lesson).

#define TT    512
#define NB    4096
#define HH    12
#define RPW   4      // rows (cells) per wave
#define CHUNK 64     // X staging chunk; TT % CHUNK == 0
#define XPAD  68     // padded row stride (floats): +4 breaks bank aliasing

typedef float v2f __attribute__((ext_vector_type(2)));

static __device__ __forceinline__ v2f pkfma(v2f a, v2f b, v2f c) {
#if __has_builtin(__builtin_elementwise_fma)
    return __builtin_elementwise_fma(a, b, c);
#else
    v2f r; r.x = fmaf(a.x, b.x, c.x); r.y = fmaf(a.y, b.y, c.y); return r;
#endif
}

#define SNEG   (-1.44269504088896340736f)   // sigmoid pre-scale: -log2(e)
#define SPOS   ( 2.88539008177792681472f)   // tanh pre-scale: +2*log2(e)
#define M2SPOS (-5.77078016355585362944f)   // -2*SPOS

#define ROR(r) (0x120 + (r))                // DPP ctrl: row_ror:r

__global__ __launch_bounds__(64, 1)
void lstm_fused(const float* __restrict__ X,
                const float* __restrict__ W_ih,
                const float* __restrict__ W_hh,
                const float* __restrict__ b_ih,
                const float* __restrict__ b_hh,
                const float* __restrict__ fc_w,
                const float* __restrict__ fc_b,
                float* __restrict__ out)
{
    __shared__ float xchunk[RPW][XPAD];   // transposed + padded: [row][time]

    const int lane = threadIdx.x;        // 0..63
    const int row  = lane >> 4;          // 0..3  : cell slot
    const int j    = lane & 15;          // 0..11 real, 12..15 clone lanes
    const int cellbase = blockIdx.x * RPW;
    const int cell = cellbase + row;     // grid sized so cell < NB always

    // ---- probe DPP ror direction: sid[r] = within-row source lane of ror r
    int sid[16];
    sid[0] = j;
#define PROBE(r) sid[r] = __builtin_amdgcn_update_dpp(0, j, ROR(r), 0xF, 0xF, true);
    PROBE(1)  PROBE(2)  PROBE(3)  PROBE(4)  PROBE(5)
    PROBE(6)  PROBE(7)  PROBE(8)  PROBE(9)  PROBE(10)
    PROBE(11) PROBE(12) PROBE(13) PROBE(14) PROBE(15)
#undef PROBE

    // ---- per-source-slot gate weight tables (r=0 is local contribution)
    const int jc = (j < HH) ? j : (HH - 1);   // clamp clone lanes (finite)
    v2f wifU[16], wgoU[16];
    #pragma unroll
    for (int r = 0; r < 16; ++r) {
        const int  s  = sid[r];
        const int  sc = (s < HH) ? s : (HH - 1);
        const float g = ((j >= HH) || (s < HH)) ? 1.0f : 0.0f;
        wifU[r].x = g * SNEG * W_hh[(0 * HH + jc) * HH + sc];
        wifU[r].y = g * SNEG * W_hh[(1 * HH + jc) * HH + sc];
        wgoU[r].x = g * SPOS * W_hh[(2 * HH + jc) * HH + sc];
        wgoU[r].y = g * SNEG * W_hh[(3 * HH + jc) * HH + sc];
    }
    v2f bif, bgo, wxif, wxgo;
    bif.x  = SNEG * (b_ih[0 * HH + jc] + b_hh[0 * HH + jc]);
    bif.y  = SNEG * (b_ih[1 * HH + jc] + b_hh[1 * HH + jc]);
    bgo.x  = SPOS * (b_ih[2 * HH + jc] + b_hh[2 * HH + jc]);
    bgo.y  = SNEG * (b_ih[3 * HH + jc] + b_hh[3 * HH + jc]);
    wxif.x = SNEG * W_ih[0 * HH + jc];   // IN == 1, W_ih flat [48]
    wxif.y = SNEG * W_ih[1 * HH + jc];
    wxgo.x = SPOS * W_ih[2 * HH + jc];
    wxgo.y = SNEG * W_ih[3 * HH + jc];
    const float fcb  = fc_b[0];
    const float fcwj = (j < HH) ? fc_w[j] : 0.0f;   // clones contribute 0

    float c2 = 0.0f;     // pre-scaled cell state: SPOS * c[cell][j]
    float hn = 0.0f;     // my h element h[cell][j]  (h0 = 0)
    int hbits = 0;

    // delayed-output state: pPend = prev step's hn*fcwj (lane partial),
    // offPrev = byte offset of prev step's row in out. offPrev=0 at t=0
    // makes the first (fake) store alias out[0][cell]; the real t=0 store
    // overwrites it one step later (same lane, same address, in order).
    float pPend = 0.0f;
    unsigned offPrev = 0;
    float* const outp = out + cell;

    // prefetch chunk 0 of X into registers
    float4 gq = *(const float4*)(X + (size_t)lane * NB + cellbase);

    for (int tc = 0; tc < TT; tc += CHUNK) {
        // stage prefetched chunk to LDS (transposed/padded), prefetch next
        xchunk[0][lane] = gq.x;
        xchunk[1][lane] = gq.y;
        xchunk[2][lane] = gq.z;
        xchunk[3][lane] = gq.w;
        if (tc + CHUNK < TT)
            gq = *(const float4*)(X + (size_t)(tc + CHUNK + lane) * NB + cellbase);

        // x for the first 4-step group of this chunk (only load that can
        // stall on lgkm; once per 64 steps)
        float4 xq_next = *(const float4*)&xchunk[row][0];

        for (int t4 = 0; t4 < CHUNK; t4 += 4) {
            const float4 xq = xq_next;                      // group t4 (prefetched)
            const int nx = (t4 + 4 < CHUNK) ? (t4 + 4) : t4; // clamp: last group re-reads self
            xq_next = *(const float4*)&xchunk[row][nx];      // prefetch group t4+4
            const float xs[4] = {xq.x, xq.y, xq.z, xq.w};

            #pragma unroll
            for (int u = 0; u < 4; ++u) {
                // chain HEAD: bias + x-projection (operands ready a group
                // early -> scheduler hoists; off the h-critical path)
                v2f xvv; xvv.x = xs[u]; xvv.y = xs[u];
                v2f gifA = pkfma(xvv, wxif, bif);
                v2f goA  = pkfma(xvv, wxgo, bgo);
                v2f gifB; gifB.x = 0.0f; gifB.y = 0.0f;
                v2f goB;  goB.x  = 0.0f; goB.y  = 0.0f;
                {   // local contribution (r = 0)
                    v2f hk; hk.x = hn; hk.y = hn;
                    gifA = pkfma(wifU[0], hk, gifA);
                    goA  = pkfma(wgoU[0], hk, goA);
                }
#define XR(r) { \
                const int hr_##r = __builtin_amdgcn_update_dpp(0, hbits, ROR(r), 0xF, 0xF, true); \
                const float hf = __int_as_float(hr_##r); \
                v2f hk; hk.x = hf; hk.y = hf; \
                if ((r) < 8) { gifA = pkfma(wifU[r], hk, gifA); goA = pkfma(wgoU[r], hk, goA); } \
                else         { gifB = pkfma(wifU[r], hk, gifB); goB = pkfma(wgoU[r], hk, goB); } }
                XR(1)  XR(2)  XR(3)  XR(4)  XR(5)
                XR(6)  XR(7)  XR(8)  XR(9)  XR(10)
                XR(11) XR(12) XR(13) XR(14) XR(15)
#undef XR
                const v2f gif = gifA + gifB;     // v_pk_add_f32
                const v2f ggo = goA + goB;

                // gate exponentials (pair-1 of the serial trans path)
                const float Ei = __builtin_amdgcn_exp2f(gif.x);
                const float Ef = __builtin_amdgcn_exp2f(gif.y);
                const float Eg = __builtin_amdgcn_exp2f(ggo.x);
                const float Eo = __builtin_amdgcn_exp2f(ggo.y);

                // delayed fc-reduce (PREVIOUS step), first half: fills the
                // exp2->rcp stall window (incl. its own DPP RAW bubbles)
                float p = pPend;
                p += __int_as_float(__builtin_amdgcn_update_dpp(0, __float_as_int(p), ROR(8), 0xF, 0xF, true));
                p += __int_as_float(__builtin_amdgcn_update_dpp(0, __float_as_int(p), ROR(4), 0xF, 0xF, true));

                const float si = __builtin_amdgcn_rcpf(1.0f + Ei);
                const float sf = __builtin_amdgcn_rcpf(1.0f + Ef);
                const float rg = __builtin_amdgcn_rcpf(1.0f + Eg);
                const float so = __builtin_amdgcn_rcpf(1.0f + Eo);

                // pre-scaled cell update: c2 = sf*c2 + si*(SPOS*tanh-arg)
                const float tgS = fmaf(M2SPOS, rg, SPOS);
                c2 = fmaf(sf, c2, si * tgS);
                const float Ec = __builtin_amdgcn_exp2f(c2);   // exp2(SPOS*c)

                // delayed fc-reduce, second half + store: fills the
                // tanh(c) exp2->rcp window
                p += __int_as_float(__builtin_amdgcn_update_dpp(0, __float_as_int(p), ROR(2), 0xF, 0xF, true));
                p += __int_as_float(__builtin_amdgcn_update_dpp(0, __float_as_int(p), ROR(1), 0xF, 0xF, true));
                if (j == 0) *(float*)((char*)outp + offPrev) = p + fcb;

                const float rc   = __builtin_amdgcn_rcpf(1.0f + Ec);
                const float m2so = -2.0f * so;
                hn    = fmaf(m2so, rc, so);
                hbits = __float_as_int(hn);

                // stage this step's output partial for next step's windows
                pPend   = hn * fcwj;
                offPrev = (unsigned)(tc + t4 + u) << 14;   // this step * NB * 4B
            }
        }
    }

    // epilogue: flush the final pending output (t = 511)
    {
        float p = pPend;
        p += __int_as_float(__builtin_amdgcn_update_dpp(0, __float_as_int(p), ROR(8), 0xF, 0xF, true));
        p += __int_as_float(__builtin_amdgcn_update_dpp(0, __float_as_int(p), ROR(4), 0xF, 0xF, true));
        p += __int_as_float(__builtin_amdgcn_update_dpp(0, __float_as_int(p), ROR(2), 0xF, 0xF, true));
        p += __int_as_float(__builtin_amdgcn_update_dpp(0, __float_as_int(p), ROR(1), 0xF, 0xF, true));
        if (j == 0) *(float*)((char*)outp + offPrev) = p + fcb;
    }
}

extern "C" void kernel_launch(void* const* d_in, const int* in_sizes, int n_in,
                              void* d_out, int out_size, void* d_ws, size_t ws_size,
                              hipStream_t stream) {
    const float* X    = (const float*)d_in[0];
    const float* W_ih = (const float*)d_in[1];
    const float* W_hh = (const float*)d_in[2];
    const float* b_ih = (const float*)d_in[3];
    const float* b_hh = (const float*)d_in[4];
    const float* fc_w = (const float*)d_in[5];
    const float* fc_b = (const float*)d_in[6];
    float* out = (float*)d_out;

    const int grid = NB / RPW;   // 1024 single-wave blocks: every SIMD busy
    lstm_fused<<<grid, 64, 0, stream>>>(X, W_ih, W_hh, b_ih, b_hh, fc_w, fc_b, out);
}

// Round 2
// 177.086 us; speedup vs baseline: 1.0320x; 1.0289x over previous
//
#include <hip/hip_runtime.h>

// LSTM: T=512, B=4096, IN=1, H=12.
// R12: replace the DPP-ror h-exchange + per-source gate tables with an
// LDS-broadcast, IN-LANE pairwise matvec. Rationale (R11 counters:
// VALUBusy 62%, Occ 11% = 1 wave/SIMD, HBM 4.6%, conflicts 0):
// the step body issued ~75 VALU of which 19 DPP movs + 8 zero-gated clone
// pkfmas are pure exchange overhead; a counting argument shows 15 rors is
// already optimal for the 16-lane ring, so the decomposition itself was at
// its floor. New scheme per step:
//   - hn -> 1 ds_write_b32; row h[0..11] read back as 3 broadcast
//     ds_read_b128 (same-wave DS ops are in-order; reads conflict-free at
//     row stride 20: banks {0-3,20-23,8-11,28-31} etc. disjoint per read).
//   - each lane owns full h -> gate g = sum over 6 v_pk_fma_f32 on
//     (h[2k],h[2k+1]) pairs straight from float4 subregs: no shuffles, no
//     movs, no clone-source fmas. x-proj + bias folded into a packed init
//     fma via (wx,0),(b,0) constant pairs.
//   - fc dot in-lane too (init pkfma carries fc_b; 5 pkfma + 1 hadd),
//     replacing mul + 4 DPP + 4 add. Keeps R11's delayed-one-step
//     placement (consumes h_{t-1} read this iter) so it fills the
//     exp2->rcp stall windows; same out[0]-alias boundary trick (passed
//     R11); epilogue flushes t=511.
// Instruction budget ~75 VALU (19 DPP) -> ~55 VALU + 4 DS, DPP count 0.
// Added LDS round trip (~60-80 cyc) sits on the serial chain but measured
// stall headroom (~38% of step) + fc/head filler covers it.
//
// Retained from R10/R11: 4 cells/wave (16 lanes per cell, lanes 12-15
// clones; clones now write to distinct dump slots 12-15 and are otherwise
// inert), 1024 single-wave blocks (every SIMD busy), X staged in chunks of
// 64 to LDS transposed+padded (XPAD=68), xq group prefetch one 4-step
// group ahead, pre-scaled gates (sigmoid -log2e, tanh +2log2e) so
// activations are rcp(1+exp2(g)), pre-scaled cell state c2 = 2log2e*c,
// launch_bounds(64,1).

#define TT    512
#define NB    4096
#define HH    12
#define RPW   4      // rows (cells) per wave
#define CHUNK 64     // X staging chunk; TT % CHUNK == 0
#define XPAD  68     // padded row stride (floats): breaks bank aliasing
#define HSTR  20     // h row stride (floats): 80B, 16B-aligned, banks spread

typedef float v2f __attribute__((ext_vector_type(2)));
typedef float v4f __attribute__((ext_vector_type(4)));

static __device__ __forceinline__ v2f pkfma(v2f a, v2f b, v2f c) {
#if __has_builtin(__builtin_elementwise_fma)
    return __builtin_elementwise_fma(a, b, c);
#else
    v2f r; r.x = fmaf(a.x, b.x, c.x); r.y = fmaf(a.y, b.y, c.y); return r;
#endif
}

#define SNEG   (-1.44269504088896340736f)   // sigmoid pre-scale: -log2(e)
#define SPOS   ( 2.88539008177792681472f)   // tanh pre-scale: +2*log2(e)
#define M2SPOS (-5.77078016355585362944f)   // -2*SPOS

__global__ __launch_bounds__(64, 1)
void lstm_fused(const float* __restrict__ X,
                const float* __restrict__ W_ih,
                const float* __restrict__ W_hh,
                const float* __restrict__ b_ih,
                const float* __restrict__ b_hh,
                const float* __restrict__ fc_w,
                const float* __restrict__ fc_b,
                float* __restrict__ out)
{
    __shared__ __align__(16) float xchunk[RPW][XPAD]; // [row][time], padded
    __shared__ __align__(16) float hsh[RPW][HSTR];    // [row][h-slot]

    const int lane = threadIdx.x;        // 0..63
    const int row  = lane >> 4;          // 0..3  : cell slot
    const int j    = lane & 15;          // 0..11 real, 12..15 clone lanes
    const int cellbase = blockIdx.x * RPW;
    const int cell = cellbase + row;     // grid sized so cell < NB always

    const int jc = (j < HH) ? j : (HH - 1);   // clamp clone lanes (finite)

    // ---- in-lane pairwise weights: per gate, 6 v2f of (W[s],W[s+1]),
    // pre-scaled (i,f,o: SNEG; g: SPOS). Rows of W_hh are contiguous [12].
    v2f wI[6], wF[6], wG[6], wO[6], fcv[6];
    #pragma unroll
    for (int k = 0; k < 6; ++k) {
        const float* r0 = W_hh + (0 * HH + jc) * HH + 2 * k;
        const float* r1 = W_hh + (1 * HH + jc) * HH + 2 * k;
        const float* r2 = W_hh + (2 * HH + jc) * HH + 2 * k;
        const float* r3 = W_hh + (3 * HH + jc) * HH + 2 * k;
        wI[k].x = SNEG * r0[0];  wI[k].y = SNEG * r0[1];
        wF[k].x = SNEG * r1[0];  wF[k].y = SNEG * r1[1];
        wG[k].x = SPOS * r2[0];  wG[k].y = SPOS * r2[1];
        wO[k].x = SNEG * r3[0];  wO[k].y = SNEG * r3[1];
        fcv[k].x = fc_w[2 * k];  fcv[k].y = fc_w[2 * k + 1];
    }
    // head constants: init acc_g = pkfma((x,x), (wx_g,0), (b_g,0))
    v2f wxI, wxF, wxG, wxO, bI, bF, bG, bO, bFC;
    wxI.x = SNEG * W_ih[0 * HH + jc];  wxI.y = 0.0f;
    wxF.x = SNEG * W_ih[1 * HH + jc];  wxF.y = 0.0f;
    wxG.x = SPOS * W_ih[2 * HH + jc];  wxG.y = 0.0f;
    wxO.x = SNEG * W_ih[3 * HH + jc];  wxO.y = 0.0f;
    bI.x = SNEG * (b_ih[0 * HH + jc] + b_hh[0 * HH + jc]);  bI.y = 0.0f;
    bF.x = SNEG * (b_ih[1 * HH + jc] + b_hh[1 * HH + jc]);  bF.y = 0.0f;
    bG.x = SPOS * (b_ih[2 * HH + jc] + b_hh[2 * HH + jc]);  bG.y = 0.0f;
    bO.x = SNEG * (b_ih[3 * HH + jc] + b_hh[3 * HH + jc]);  bO.y = 0.0f;
    bFC.x = fc_b[0];  bFC.y = 0.0f;     // fc bias folded into fc init

    float c2 = 0.0f;     // pre-scaled cell state: SPOS * c[cell][j]
    float hn = 0.0f;     // my h element h[cell][j]  (h0 = 0)

    float* const hrow = &hsh[row][0];
    // every lane has a distinct write slot; clones dump to 12..15 (never read)
    const int wslot = j;

    // delayed-output state (R11 trick): iteration t computes fc(h_{t-1});
    // first (fake) store aliases out[0][cell], overwritten next iteration.
    unsigned offPrev = 0;
    float* const outp = out + cell;

    // initial h0 = 0 into LDS (same-wave DS in-order vs later reads)
    hrow[wslot] = 0.0f;
    __builtin_amdgcn_wave_barrier();

    // prefetch chunk 0 of X into registers
    float4 gq = *(const float4*)(X + (size_t)lane * NB + cellbase);

    for (int tc = 0; tc < TT; tc += CHUNK) {
        // stage prefetched chunk to LDS (transposed/padded), prefetch next
        xchunk[0][lane] = gq.x;
        xchunk[1][lane] = gq.y;
        xchunk[2][lane] = gq.z;
        xchunk[3][lane] = gq.w;
        if (tc + CHUNK < TT)
            gq = *(const float4*)(X + (size_t)(tc + CHUNK + lane) * NB + cellbase);

        float4 xq_next = *(const float4*)&xchunk[row][0];

        for (int t4 = 0; t4 < CHUNK; t4 += 4) {
            const float4 xq = xq_next;                       // group t4
            const int nx = (t4 + 4 < CHUNK) ? (t4 + 4) : t4; // clamp tail
            xq_next = *(const float4*)&xchunk[row][nx];      // prefetch next
            const float xs[4] = {xq.x, xq.y, xq.z, xq.w};

            #pragma unroll
            for (int u = 0; u < 4; ++u) {
                // broadcast-read the row's h_{t-1} (3x ds_read_b128,
                // disjoint banks across rows by stride-20 layout)
                const v4f ha = *(const v4f*)&hrow[0];
                const v4f hb = *(const v4f*)&hrow[4];
                const v4f hc = *(const v4f*)&hrow[8];
                v2f hp0; hp0.x = ha.x; hp0.y = ha.y;
                v2f hp1; hp1.x = ha.z; hp1.y = ha.w;
                v2f hp2; hp2.x = hb.x; hp2.y = hb.y;
                v2f hp3; hp3.x = hb.z; hp3.y = hb.w;
                v2f hp4; hp4.x = hc.x; hp4.y = hc.y;
                v2f hp5; hp5.x = hc.z; hp5.y = hc.w;

                // gate chains: packed init (x-proj + bias), then 6 pair fmas
                v2f xvv; xvv.x = xs[u]; xvv.y = xs[u];
                v2f aI = pkfma(xvv, wxI, bI);
                v2f aF = pkfma(xvv, wxF, bF);
                v2f aG = pkfma(xvv, wxG, bG);
                v2f aO = pkfma(xvv, wxO, bO);
                // fc of h_{t-1} (delayed output), bias pre-folded: pure
                // filler for the trans windows below
                v2f pf = pkfma(fcv[0], hp0, bFC);
                aI = pkfma(wI[0], hp0, aI);  aF = pkfma(wF[0], hp0, aF);
                aG = pkfma(wG[0], hp0, aG);  aO = pkfma(wO[0], hp0, aO);
                aI = pkfma(wI[1], hp1, aI);  aF = pkfma(wF[1], hp1, aF);
                aG = pkfma(wG[1], hp1, aG);  aO = pkfma(wO[1], hp1, aO);
                pf = pkfma(fcv[1], hp1, pf);
                aI = pkfma(wI[2], hp2, aI);  aF = pkfma(wF[2], hp2, aF);
                aG = pkfma(wG[2], hp2, aG);  aO = pkfma(wO[2], hp2, aO);
                pf = pkfma(fcv[2], hp2, pf);
                aI = pkfma(wI[3], hp3, aI);  aF = pkfma(wF[3], hp3, aF);
                aG = pkfma(wG[3], hp3, aG);  aO = pkfma(wO[3], hp3, aO);
                pf = pkfma(fcv[3], hp3, pf);
                aI = pkfma(wI[4], hp4, aI);  aF = pkfma(wF[4], hp4, aF);
                aG = pkfma(wG[4], hp4, aG);  aO = pkfma(wO[4], hp4, aO);
                pf = pkfma(fcv[4], hp4, pf);
                aI = pkfma(wI[5], hp5, aI);  aF = pkfma(wF[5], hp5, aF);
                aG = pkfma(wG[5], hp5, aG);  aO = pkfma(wO[5], hp5, aO);
                pf = pkfma(fcv[5], hp5, pf);

                const float gi = aI.x + aI.y;
                const float gf = aF.x + aF.y;
                const float gg = aG.x + aG.y;
                const float go = aO.x + aO.y;

                const float Ei = __builtin_amdgcn_exp2f(gi);
                const float Ef = __builtin_amdgcn_exp2f(gf);
                const float Eg = __builtin_amdgcn_exp2f(gg);
                const float Eo = __builtin_amdgcn_exp2f(go);

                // delayed output store: fills the gate exp2->rcp window
                const float p = pf.x + pf.y;
                if (j == 0) *(float*)((char*)outp + offPrev) = p;

                const float si = __builtin_amdgcn_rcpf(1.0f + Ei);
                const float sf = __builtin_amdgcn_rcpf(1.0f + Ef);
                const float rg = __builtin_amdgcn_rcpf(1.0f + Eg);
                const float so = __builtin_amdgcn_rcpf(1.0f + Eo);

                // pre-scaled cell update
                const float tgS = fmaf(M2SPOS, rg, SPOS);
                c2 = fmaf(sf, c2, si * tgS);
                const float Ec = __builtin_amdgcn_exp2f(c2);   // exp2(SPOS*c)
                const float rc = __builtin_amdgcn_rcpf(1.0f + Ec);
                const float m2so = -2.0f * so;
                hn = fmaf(m2so, rc, so);

                // publish h_t for next iteration's broadcast read
                hrow[wslot] = hn;
                __builtin_amdgcn_wave_barrier();

                offPrev = (unsigned)(tc + t4 + u) << 14;   // t * NB * 4B
            }
        }
    }

    // epilogue: fc(h_511) -> out[511]
    {
        const v4f ha = *(const v4f*)&hrow[0];
        const v4f hb = *(const v4f*)&hrow[4];
        const v4f hc = *(const v4f*)&hrow[8];
        v2f hp0; hp0.x = ha.x; hp0.y = ha.y;
        v2f hp1; hp1.x = ha.z; hp1.y = ha.w;
        v2f hp2; hp2.x = hb.x; hp2.y = hb.y;
        v2f hp3; hp3.x = hb.z; hp3.y = hb.w;
        v2f hp4; hp4.x = hc.x; hp4.y = hc.y;
        v2f hp5; hp5.x = hc.z; hp5.y = hc.w;
        v2f pf = pkfma(fcv[0], hp0, bFC);
        pf = pkfma(fcv[1], hp1, pf);
        pf = pkfma(fcv[2], hp2, pf);
        pf = pkfma(fcv[3], hp3, pf);
        pf = pkfma(fcv[4], hp4, pf);
        pf = pkfma(fcv[5], hp5, pf);
        const float p = pf.x + pf.y;
        if (j == 0) *(float*)((char*)outp + offPrev) = p;
    }
}

extern "C" void kernel_launch(void* const* d_in, const int* in_sizes, int n_in,
                              void* d_out, int out_size, void* d_ws, size_t ws_size,
                              hipStream_t stream) {
    const float* X    = (const float*)d_in[0];
    const float* W_ih = (const float*)d_in[1];
    const float* W_hh = (const float*)d_in[2];
    const float* b_ih = (const float*)d_in[3];
    const float* b_hh = (const float*)d_in[4];
    const float* fc_w = (const float*)d_in[5];
    const float* fc_b = (const float*)d_in[6];
    float* out = (float*)d_out;

    const int grid = NB / RPW;   // 1024 single-wave blocks: every SIMD busy
    lstm_fused<<<grid, 64, 0, stream>>>(X, W_ih, W_hh, b_ih, b_hh, fc_w, fc_b, out);
}